// Round 23
// baseline (704.803 us; speedup 1.0000x reference)
//
#include <hip/hip_runtime.h>

// HeteroGNN: 2-layer hetero SAGE (gene/disease/compound), H=128.
// R23 = R22/R20 (best, ~311us) + ONE parameter change, bit-identical math:
//  - k_gemm_all: __launch_bounds__(256,5) -> 5 blocks/CU (5 x 32KB = 160KB
//    LDS, exactly the MI355X capacity; VGPR 64 fits easily). The GEMM is
//    latency-bound (MfmaUtil 10%, occ 30%); +25% resident waves is the one
//    lever that consistently helped (R14, R20) and changes nothing else.
// Pipeline: memset, convert(NT loads), binA(EPB=1024), binB(512thr, PADRES),
// prepw, L0{agg,gemm}, L1{agg,gemm} = 9 launches.

constexpr int HD = 128;
constexpr int NBMAX = 512;      // max buckets (Ntot/1024 = 293 here)
constexpr int BSTRIDE = 32768;  // per-bucket record capacity
constexpr int EPB = 1024;       // edges per binA block (~8 blocks/CU)
constexpr int PADRES = 7176;    // per-bucket pad reserve (1024*7 + 8)

typedef __attribute__((ext_vector_type(8))) short bf16x8;
typedef __attribute__((ext_vector_type(16))) float f32x16;
typedef __attribute__((ext_vector_type(2))) float f32x2;
typedef __attribute__((ext_vector_type(4))) float f32x4;
typedef __attribute__((ext_vector_type(4))) unsigned int u32x4;

__device__ __forceinline__ unsigned short f2bf(float x) {
  unsigned u = __builtin_bit_cast(unsigned, x);
  u += 0x7FFF + ((u >> 16) & 1);  // RNE
  return (unsigned short)(u >> 16);
}
__device__ __forceinline__ float bf2f(unsigned short h) {
  return __builtin_bit_cast(float, (unsigned)h << 16);
}

// pack 8 f32 (x16 scale) -> 8 fp8 bytes (uint2)
__device__ __forceinline__ uint2 pack_fp8x8(const float* v) {
  uint2 o;
  unsigned t;
  t = (unsigned)__builtin_amdgcn_cvt_pk_fp8_f32(v[0] * 16.f, v[1] * 16.f, 0, false);
  t = (unsigned)__builtin_amdgcn_cvt_pk_fp8_f32(v[2] * 16.f, v[3] * 16.f, (int)t, true);
  o.x = t;
  t = (unsigned)__builtin_amdgcn_cvt_pk_fp8_f32(v[4] * 16.f, v[5] * 16.f, 0, false);
  t = (unsigned)__builtin_amdgcn_cvt_pk_fp8_f32(v[6] * 16.f, v[7] * 16.f, (int)t, true);
  o.y = t;
  return o;
}

// ---------------- f32 -> bf16 + fp8 table convert ----------------
__global__ __launch_bounds__(256) void k_convert(const float* __restrict__ s0,
                                                 const float* __restrict__ s1,
                                                 const float* __restrict__ s2,
                                                 unsigned short* __restrict__ d0,
                                                 unsigned short* __restrict__ d1,
                                                 unsigned short* __restrict__ d2,
                                                 unsigned char* __restrict__ e0,
                                                 unsigned char* __restrict__ e2,
                                                 long long n0, long long n1, long long n2) {
  long long i = ((long long)blockIdx.x * 256 + threadIdx.x) * 8;
  const float* s;
  unsigned short* d;
  unsigned char* e;
  if (i < n0) { s = s0 + i; d = d0 + i; e = e0 + i; }
  else if (i < n0 + n1) { s = s1 + (i - n0); d = d1 + (i - n0); e = nullptr; }  // disease: no fp8
  else if (i < n0 + n1 + n2) { s = s2 + (i - n0 - n1); d = d2 + (i - n0 - n1); e = e2 + (i - n0 - n1); }
  else return;
  f32x4 a = __builtin_nontemporal_load((const f32x4*)s);       // single-use stream
  f32x4 b = __builtin_nontemporal_load((const f32x4*)(s + 4));
  float v[8] = {a.x, a.y, a.z, a.w, b.x, b.y, b.z, b.w};
  uint4 o;
  o.x = (unsigned)f2bf(v[0]) | ((unsigned)f2bf(v[1]) << 16);
  o.y = (unsigned)f2bf(v[2]) | ((unsigned)f2bf(v[3]) << 16);
  o.z = (unsigned)f2bf(v[4]) | ((unsigned)f2bf(v[5]) << 16);
  o.w = (unsigned)f2bf(v[6]) | ((unsigned)f2bf(v[7]) << 16);
  *(uint4*)d = o;
  if (e) *(uint2*)e = pack_fp8x8(v);
}

// ---------------- CSR build ----------------
struct GArgs {
  const int* esrc[4];
  const int* edst[4];
  int ebase[5];  // edge prefix over concatenated edge space
  int nbase[4];  // dst-node prefix per relation (concat node space)
};

// Pass A: bin edges into 1024-node buckets; rec = (g&1023)<<20 | src.
__global__ __launch_bounds__(256) void k_binA(GArgs ga, int Etot, int NB,
                                              int* __restrict__ bucketCur,
                                              unsigned* __restrict__ binned) {
  __shared__ int hist[NBMAX];
  __shared__ int base[NBMAX];
  const int tid = threadIdx.x;
  for (int j = tid; j < NB; j += 256) hist[j] = 0;
  __syncthreads();
  const int e0 = blockIdx.x * EPB;
  for (int i = tid; i < EPB; i += 256) {
    int e = e0 + i;
    if (e < Etot) {
      int r = (e >= ga.ebase[1]) + (e >= ga.ebase[2]) + (e >= ga.ebase[3]);
      int g = ga.nbase[r] + ga.edst[r][e - ga.ebase[r]];
      atomicAdd(&hist[g >> 10], 1);
    }
  }
  __syncthreads();
  for (int j = tid; j < NB; j += 256) {
    int h = hist[j];
    base[j] = h ? atomicAdd(&bucketCur[j], h) : 0;
    hist[j] = 0;  // same thread owns j in both statements -> ordered
  }
  __syncthreads();
  for (int i = tid; i < EPB; i += 256) {
    int e = e0 + i;
    if (e < Etot) {
      int r = (e >= ga.ebase[1]) + (e >= ga.ebase[2]) + (e >= ga.ebase[3]);
      int el = e - ga.ebase[r];
      int g = ga.nbase[r] + ga.edst[r][el];
      int bk = g >> 10;
      int pos = base[bk] + atomicAdd(&hist[bk], 1);
      binned[(size_t)bk * BSTRIDE + pos] =
          ((unsigned)(g & 1023) << 20) | (unsigned)ga.esrc[r][el];
    }
  }
}

// Pass B: per-bucket CSR finalize, 512 threads; segments padded to 8 so the
// aggregate can load index quads via broadcast uint4.
__global__ __launch_bounds__(512) void k_binB(const int* __restrict__ bucketCur,
                                              const unsigned* __restrict__ binned,
                                              int* __restrict__ ptr, int* __restrict__ cnt,
                                              int* __restrict__ ss, int Ntot) {
  const int b = blockIdx.x;
  const int tid = threadIdx.x;
  __shared__ int ncnt[1024];
  __shared__ int noff[1024];
  __shared__ int red[512];
  __shared__ int sbase_s;
  __shared__ int wsum[8], wbase[8];

  int part = 0;
  for (int i = tid; i < b; i += 512) part += bucketCur[i];
  red[tid] = part;
  __syncthreads();
  for (int s = 256; s > 0; s >>= 1) {
    if (tid < s) red[tid] += red[tid + s];
    __syncthreads();
  }
  if (tid == 0) sbase_s = ((red[0] + 7) & ~7) + b * PADRES;  // 8-aligned base

  for (int j = tid; j < 1024; j += 512) ncnt[j] = 0;
  __syncthreads();

  const int ecount = bucketCur[b];
  const unsigned* bp = binned + (size_t)b * BSTRIDE;
  for (int i = tid; i < ecount; i += 512) atomicAdd(&ncnt[bp[i] >> 20], 1);
  __syncthreads();

  // exclusive scan over PADDED counts (2 nodes/thread, 8-wave scan)
  const int j0 = tid * 2;
  int c0 = ncnt[j0], c1 = ncnt[j0 + 1];
  int p0 = (c0 + 7) & ~7, p1 = (c1 + 7) & ~7;
  int s2 = p0 + p1;
  int lane = tid & 63, wid = tid >> 6;
  int incl = s2;
#pragma unroll
  for (int off = 1; off < 64; off <<= 1) {
    int t = __shfl_up(incl, off);
    if (lane >= off) incl += t;
  }
  if (lane == 63) wsum[wid] = incl;
  __syncthreads();
  if (tid == 0) {
    int acc = 0;
#pragma unroll
    for (int w2 = 0; w2 < 8; ++w2) { wbase[w2] = acc; acc += wsum[w2]; }
  }
  __syncthreads();
  int excl = wbase[wid] + incl - s2;
  const int sbase = sbase_s;
  int o0 = excl, o1 = o0 + p0;
  noff[j0] = o0; noff[j0 + 1] = o1;
  int g0 = b * 1024 + j0;
  if (g0 + 0 < Ntot) { ptr[g0 + 0] = sbase + o0; cnt[g0 + 0] = c0; }
  if (g0 + 1 < Ntot) { ptr[g0 + 1] = sbase + o1; cnt[g0 + 1] = c1; }
  __syncthreads();

  for (int i = tid; i < ecount; i += 512) {
    unsigned rec = bp[i];
    int j = rec >> 20;
    int p = sbase + atomicAdd(&noff[j], 1);
    ss[p] = (int)(rec & 0xFFFFF);
  }
}

// ---------------- W preprocessing ----------------
// W (or Wa+Wb) [k][n] f32 -> transposed [n][k] bf16, k swizzled:
// idx = n*128 + (k ^ ((n&15)<<3))  -> conflict-free ds_read_b128 in GEMM.
struct PrepArgs {
  const float* a[14];
  const float* b[14];
};

__global__ __launch_bounds__(256) void k_prepw(PrepArgs pa, unsigned short* __restrict__ out) {
  int s = blockIdx.x;
  const float* A = pa.a[s];
  const float* B = pa.b[s];
  unsigned short* oh = out + (size_t)s * 16384;
  int e0 = blockIdx.y * 1024 + threadIdx.x * 4;
#pragma unroll
  for (int j = 0; j < 4; ++j) {
    int e = e0 + j;
    int k = e >> 7, n = e & 127;
    float v = A[e] + (B ? B[e] : 0.f);
    oh[n * 128 + (k ^ ((n & 15) << 3))] = f2bf(v);
  }
}

// ---------------- fused neighbor mean (4 relations, fp8 gather) ----------------
struct AArgs {
  const unsigned char* xs[4];   // fp8 tables (x16 scale)
  unsigned short* mean[4];      // bf16 out
  int nbase[4];
  int bbase[5];  // block prefix
  int n[4];
};

__global__ __launch_bounds__(256) void k_aggregate_all(AArgs A, const int* __restrict__ ptr,
                                                       const int* __restrict__ cnt,
                                                       const int* __restrict__ ss) {
  int b = blockIdx.x;
  int r = (b >= A.bbase[1]) + (b >= A.bbase[2]) + (b >= A.bbase[3]);
  int d = (b - A.bbase[r]) * 32 + (threadIdx.x >> 3);
  if (d >= A.n[r]) return;
  const unsigned char* xs = A.xs[r];
  int l = threadIdx.x & 7;
  int g = A.nbase[r] + d;
  int p = ptr[g];   // multiple of 8 -> 16B-aligned index loads
  int deg = cnt[g];
  f32x2 b0 = {0.f, 0.f}, b1 = {0.f, 0.f}, b2 = {0.f, 0.f}, b3 = {0.f, 0.f};
  f32x2 b4 = {0.f, 0.f}, b5 = {0.f, 0.f}, b6 = {0.f, 0.f}, b7 = {0.f, 0.f};
  for (int j0 = 0; j0 < deg; j0 += 8) {
    int m = deg - j0;
    if (m > 8) m = 8;
    const uint4* ip = (const uint4*)(ss + p + j0);
    uint4 ia = ip[0];          // same addr across lanes -> broadcast
    uint4 ib = ip[1];          // pad slots may hold garbage; guarded below
    uint4 uu[8];
    if (m > 0) uu[0] = *(const uint4*)(xs + (size_t)ia.x * HD + l * 16);
    if (m > 1) uu[1] = *(const uint4*)(xs + (size_t)ia.y * HD + l * 16);
    if (m > 2) uu[2] = *(const uint4*)(xs + (size_t)ia.z * HD + l * 16);
    if (m > 3) uu[3] = *(const uint4*)(xs + (size_t)ia.w * HD + l * 16);
    if (m > 4) uu[4] = *(const uint4*)(xs + (size_t)ib.x * HD + l * 16);
    if (m > 5) uu[5] = *(const uint4*)(xs + (size_t)ib.y * HD + l * 16);
    if (m > 6) uu[6] = *(const uint4*)(xs + (size_t)ib.z * HD + l * 16);
    if (m > 7) uu[7] = *(const uint4*)(xs + (size_t)ib.w * HD + l * 16);
#pragma unroll
    for (int k = 0; k < 8; ++k) {
      if (k < m) {
        b0 += __builtin_amdgcn_cvt_pk_f32_fp8(uu[k].x, false);
        b1 += __builtin_amdgcn_cvt_pk_f32_fp8(uu[k].x, true);
        b2 += __builtin_amdgcn_cvt_pk_f32_fp8(uu[k].y, false);
        b3 += __builtin_amdgcn_cvt_pk_f32_fp8(uu[k].y, true);
        b4 += __builtin_amdgcn_cvt_pk_f32_fp8(uu[k].z, false);
        b5 += __builtin_amdgcn_cvt_pk_f32_fp8(uu[k].z, true);
        b6 += __builtin_amdgcn_cvt_pk_f32_fp8(uu[k].w, false);
        b7 += __builtin_amdgcn_cvt_pk_f32_fp8(uu[k].w, true);
      }
    }
  }
  float inv = 1.0f / (16.0f * (float)(deg > 0 ? deg : 1));  // fold out x16 scale
  u32x4 o;
  u32x4* mp = (u32x4*)(A.mean[r] + (size_t)d * HD + l * 16);
  o.x = (unsigned)f2bf(b0.x * inv) | ((unsigned)f2bf(b0.y * inv) << 16);
  o.y = (unsigned)f2bf(b1.x * inv) | ((unsigned)f2bf(b1.y * inv) << 16);
  o.z = (unsigned)f2bf(b2.x * inv) | ((unsigned)f2bf(b2.y * inv) << 16);
  o.w = (unsigned)f2bf(b3.x * inv) | ((unsigned)f2bf(b3.y * inv) << 16);
  mp[0] = o;  // plain (cached) store: means are the GEMM's A-operand
  o.x = (unsigned)f2bf(b4.x * inv) | ((unsigned)f2bf(b4.y * inv) << 16);
  o.y = (unsigned)f2bf(b5.x * inv) | ((unsigned)f2bf(b5.y * inv) << 16);
  o.z = (unsigned)f2bf(b6.x * inv) | ((unsigned)f2bf(b6.y * inv) << 16);
  o.w = (unsigned)f2bf(b7.x * inv) | ((unsigned)f2bf(b7.y * inv) << 16);
  mp[1] = o;  // +16B == +8 shorts
}

// ---------------- merged MFMA GEMM (3 node types, one dispatch) ----------------
// M-tile 128, 4 waves, wave owns 32 rows (acc[4]); R14-style A prefetch.
// launch_bounds(256,5): 5 blocks/CU (160KB LDS exactly).
struct GemmArgs {
  const unsigned short* x[3][3];   // [type][slab]
  const unsigned short* wp[3][3];
  const float* b0[3];
  const float* b1[3];
  float* outf[3];                  // layer-1: d_out segment; layer-0: null
  unsigned short* outb[3];         // layer-0: bf16 hidden table
  unsigned char* out8[3];          // layer-0: fp8 hidden table (null = skip)
  int M[3];
  int nslab[3];
  int gbase[4];                    // block prefix per type
  int relu;
};

__global__ __launch_bounds__(256, 5) void k_gemm_all(GemmArgs ga) {
  __shared__ unsigned short ldsb[16384];  // 32KB
  const int t = (blockIdx.x >= ga.gbase[1]) + (blockIdx.x >= ga.gbase[2]);
  const int blk = blockIdx.x - ga.gbase[t];
  const int M = ga.M[t];
  const int nslab = ga.nslab[t];
  const int tid = threadIdx.x;
  const int wave = tid >> 6;
  const int lane = tid & 63;
  const int l31 = lane & 31;
  const int lhalf = lane >> 5;

  const int mbase = blk * 128 + wave * 32;
  int r0 = mbase + l31;
  if (r0 > M - 1) r0 = M - 1;

  f32x16 acc[4];
#pragma unroll
  for (int n = 0; n < 4; ++n)
#pragma unroll
    for (int q = 0; q < 16; ++q) acc[n][q] = 0.f;

#pragma unroll
  for (int s = 0; s < 3; ++s) {
    if (s < nslab) {
      const unsigned short* xp = ga.x[t][s] + (size_t)r0 * HD + lhalf * 8;
      // prefetch the wave's full A row for this slab: 8 independent 16B loads
      bf16x8 areg[8];
#pragma unroll
      for (int ks = 0; ks < 8; ++ks) areg[ks] = *(const bf16x8*)(xp + ks * 16);

      __syncthreads();  // protect LDS from previous slab's readers
      {
        const float4* src = (const float4*)ga.wp[t][s];
        float4* dst = (float4*)ldsb;
#pragma unroll
        for (int j = 0; j < 8; ++j) dst[tid + j * 256] = src[tid + j * 256];
      }
      __syncthreads();

#pragma unroll
      for (int ks = 0; ks < 8; ++ks) {
        const int k0 = ks * 16 + lhalf * 8;
#pragma unroll
        for (int nt = 0; nt < 4; ++nt) {
          const int rown = nt * 32 + l31;
          const int kidx = k0 ^ ((rown & 15) << 3);
          const bf16x8 bb = *(const bf16x8*)&ldsb[rown * HD + kidx];
          acc[nt] = __builtin_amdgcn_mfma_f32_32x32x16_bf16(areg[ks], bb, acc[nt], 0, 0, 0);
        }
      }
    }
  }

  const float* b0 = ga.b0[t];
  const float* b1 = ga.b1[t];
  float* outf = ga.outf[t];
  unsigned short* outb = ga.outb[t];
  unsigned char* out8 = ga.out8[t];
#pragma unroll
  for (int nt = 0; nt < 4; ++nt) {
    const int col = nt * 32 + l31;
    float bias = b0[col] + (b1 ? b1[col] : 0.f);
#pragma unroll
    for (int rg = 0; rg < 16; ++rg) {
      int row = mbase + (rg & 3) + 8 * (rg >> 2) + 4 * lhalf;
      float v = acc[nt][rg] + bias;
      if (ga.relu) v = fmaxf(v, 0.f);
      if (row < M) {
        if (outf) {
          outf[(size_t)row * HD + col] = v;
        } else {
          unsigned short h = f2bf(v);
          outb[(size_t)row * HD + col] = h;
          if (out8) {
            float vb = bf2f(h);  // bf16-rounded value (matches table semantics)
            unsigned pk = (unsigned)__builtin_amdgcn_cvt_pk_fp8_f32(vb * 16.f, vb * 16.f, 0, false);
            out8[(size_t)row * HD + col] = (unsigned char)(pk & 0xFF);
          }
        }
      }
    }
  }
}

extern "C" void kernel_launch(void* const* d_in, const int* in_sizes, int n_in,
                              void* d_out, int out_size, void* d_ws, size_t ws_size,
                              hipStream_t stream) {
  const float* emb_g = (const float*)d_in[0];
  const float* emb_d = (const float*)d_in[1];
  const float* emb_c = (const float*)d_in[2];
  const float* Wl = (const float*)d_in[3];   // [2,4,128,128]
  const float* bl = (const float*)d_in[4];   // [2,4,128]
  const float* Wr = (const float*)d_in[5];   // [2,4,128,128]

  const int NG = in_sizes[0] / HD;
  const int ND = in_sizes[1] / HD;
  const int NC = in_sizes[2] / HD;
  const int E0 = in_sizes[6];   // g->g
  const int E1 = in_sizes[8];   // c->d
  const int E2 = in_sizes[10];  // c->g
  const int E3 = in_sizes[12];  // g->c
  const int HH = HD * HD;
  const int Etot = E0 + E1 + E2 + E3;
  const int Ntot = NG + ND + NG + NC;
  const int NB = (Ntot + 1023) >> 10;  // 1024-node buckets

  // ---- workspace carve (all 16B-aligned by construction) ----
  char* w = (char*)d_ws;
  unsigned short* wprep = (unsigned short*)w; w += (size_t)14 * 32768;
  unsigned short* xbf_g0 = (unsigned short*)w; w += (size_t)NG * HD * 2;
  unsigned short* xbf_d0 = (unsigned short*)w; w += (size_t)ND * HD * 2;
  unsigned short* xbf_c0 = (unsigned short*)w; w += (size_t)NC * HD * 2;
  unsigned short* xbf_g1 = (unsigned short*)w; w += (size_t)NG * HD * 2;
  unsigned short* xbf_d1 = (unsigned short*)w; w += (size_t)ND * HD * 2;
  unsigned short* xbf_c1 = (unsigned short*)w; w += (size_t)NC * HD * 2;
  unsigned short* mean_gg = (unsigned short*)w; w += (size_t)NG * HD * 2;
  unsigned short* mean_cd = (unsigned short*)w; w += (size_t)ND * HD * 2;
  unsigned short* mean_cg = (unsigned short*)w; w += (size_t)NG * HD * 2;
  unsigned short* mean_gc = (unsigned short*)w; w += (size_t)NC * HD * 2;
  unsigned char* x8_g0 = (unsigned char*)w; w += (size_t)NG * HD;
  unsigned char* x8_c0 = (unsigned char*)w; w += (size_t)NC * HD;
  unsigned char* x8_g1 = (unsigned char*)w; w += (size_t)NG * HD;
  unsigned char* x8_c1 = (unsigned char*)w; w += (size_t)NC * HD;
  int* ss = (int*)w;        w += ((size_t)Etot + (size_t)NB * PADRES + 64) * 4;
  int* ptr = (int*)w;       w += (size_t)Ntot * 4;
  int* cnt = (int*)w;       w += (size_t)Ntot * 4;
  unsigned* binned = (unsigned*)w; w += (size_t)NB * BSTRIDE * 4;
  int* bucketCur = (int*)w; w += (size_t)NBMAX * 4;  // zeroed

  hipMemsetAsync(bucketCur, 0, (size_t)NBMAX * 4, stream);

  // bf16 (+fp8 for gene/compound) feature tables for layer 0
  {
    long long n0 = (long long)NG * HD, n1 = (long long)ND * HD, n2 = (long long)NC * HD;
    long long tot8 = (n0 + n1 + n2) / 8;
    k_convert<<<(int)((tot8 + 255) / 256), 256, 0, stream>>>(
        emb_g, emb_d, emb_c, xbf_g0, xbf_d0, xbf_c0, x8_g0, x8_c0, n0, n1, n2);
  }

  // CSR build over concatenated spaces (two-pass binned sort)
  GArgs ga;
  ga.esrc[0] = (const int*)d_in[6];  ga.edst[0] = (const int*)d_in[7];
  ga.esrc[1] = (const int*)d_in[8];  ga.edst[1] = (const int*)d_in[9];
  ga.esrc[2] = (const int*)d_in[10]; ga.edst[2] = (const int*)d_in[11];
  ga.esrc[3] = (const int*)d_in[12]; ga.edst[3] = (const int*)d_in[13];
  ga.ebase[0] = 0; ga.ebase[1] = E0; ga.ebase[2] = E0 + E1;
  ga.ebase[3] = E0 + E1 + E2; ga.ebase[4] = Etot;
  ga.nbase[0] = 0; ga.nbase[1] = NG; ga.nbase[2] = NG + ND; ga.nbase[3] = NG + ND + NG;

  k_binA<<<(Etot + EPB - 1) / EPB, 256, 0, stream>>>(ga, Etot, NB, bucketCur, binned);
  k_binB<<<NB, 512, 0, stream>>>(bucketCur, binned, ptr, cnt, ss, Ntot);

  // W preprocessing: 7 slabs/layer: 0:Wl0 1:Wl2 2:Wr0+Wr2 3:Wl1 4:Wr1 5:Wl3 6:Wr3
  PrepArgs pa;
  for (int L = 0; L < 2; ++L) {
    int b = L * 7;
    pa.a[b + 0] = Wl + (size_t)(L * 4 + 0) * HH; pa.b[b + 0] = nullptr;
    pa.a[b + 1] = Wl + (size_t)(L * 4 + 2) * HH; pa.b[b + 1] = nullptr;
    pa.a[b + 2] = Wr + (size_t)(L * 4 + 0) * HH; pa.b[b + 2] = Wr + (size_t)(L * 4 + 2) * HH;
    pa.a[b + 3] = Wl + (size_t)(L * 4 + 1) * HH; pa.b[b + 3] = nullptr;
    pa.a[b + 4] = Wr + (size_t)(L * 4 + 1) * HH; pa.b[b + 4] = nullptr;
    pa.a[b + 5] = Wl + (size_t)(L * 4 + 3) * HH; pa.b[b + 5] = nullptr;
    pa.a[b + 6] = Wr + (size_t)(L * 4 + 3) * HH; pa.b[b + 6] = nullptr;
  }
  k_prepw<<<dim3(14, 16), 256, 0, stream>>>(pa, wprep);

  float* out = (float*)d_out;
  float* xg_out = out;
  float* xd_out = out + (size_t)NG * HD;
  float* xc_out = out + (size_t)(NG + ND) * HD;

  for (int L = 0; L < 2; ++L) {
    const unsigned short* xg = L ? xbf_g1 : xbf_g0;
    const unsigned short* xd = L ? xbf_d1 : xbf_d0;
    const unsigned short* xc = L ? xbf_c1 : xbf_c0;
    const unsigned char* x8g = L ? x8_g1 : x8_g0;
    const unsigned char* x8c = L ? x8_c1 : x8_c0;

    // fused aggregates (reln order: gg(src xg), cd(src xc), cg(src xc), gc(src xg))
    AArgs aa;
    aa.xs[0] = x8g; aa.xs[1] = x8c; aa.xs[2] = x8c; aa.xs[3] = x8g;
    aa.mean[0] = mean_gg; aa.mean[1] = mean_cd; aa.mean[2] = mean_cg; aa.mean[3] = mean_gc;
    aa.nbase[0] = 0; aa.nbase[1] = NG; aa.nbase[2] = NG + ND; aa.nbase[3] = NG + ND + NG;
    aa.n[0] = NG; aa.n[1] = ND; aa.n[2] = NG; aa.n[3] = NC;
    int bb = 0;
    for (int r = 0; r < 4; ++r) { aa.bbase[r] = bb; bb += (aa.n[r] + 31) / 32; }
    aa.bbase[4] = bb;
    k_aggregate_all<<<bb, 256, 0, stream>>>(aa, ptr, cnt, ss);

    const float* bl_L = bl + (size_t)L * 4 * HD;
    const unsigned short* wp = wprep + (size_t)L * 7 * 16384;

    GemmArgs gm;
    // genes: mean_gg@Wl0 + mean_cg@Wl2 + xg@(Wr0+Wr2) + bl0 + bl2
    gm.x[0][0] = mean_gg; gm.x[0][1] = mean_cg; gm.x[0][2] = xg;
    gm.wp[0][0] = wp + 0 * 16384; gm.wp[0][1] = wp + 1 * 16384; gm.wp[0][2] = wp + 2 * 16384;
    gm.b0[0] = bl_L + 0 * HD; gm.b1[0] = bl_L + 2 * HD;
    gm.M[0] = NG; gm.nslab[0] = 3;
    // disease: mean_cd@Wl1 + xd@Wr1 + bl1
    gm.x[1][0] = mean_cd; gm.x[1][1] = xd; gm.x[1][2] = nullptr;
    gm.wp[1][0] = wp + 3 * 16384; gm.wp[1][1] = wp + 4 * 16384; gm.wp[1][2] = nullptr;
    gm.b0[1] = bl_L + 1 * HD; gm.b1[1] = nullptr;
    gm.M[1] = ND; gm.nslab[1] = 2;
    // compound: mean_gc@Wl3 + xc@Wr3 + bl3
    gm.x[2][0] = mean_gc; gm.x[2][1] = xc; gm.x[2][2] = nullptr;
    gm.wp[2][0] = wp + 5 * 16384; gm.wp[2][1] = wp + 6 * 16384; gm.wp[2][2] = nullptr;
    gm.b0[2] = bl_L + 3 * HD; gm.b1[2] = nullptr;
    gm.M[2] = NC; gm.nslab[2] = 2;
    if (L) {
      gm.outf[0] = xg_out; gm.outf[1] = xd_out; gm.outf[2] = xc_out;
      gm.outb[0] = gm.outb[1] = gm.outb[2] = nullptr;
      gm.out8[0] = gm.out8[1] = gm.out8[2] = nullptr;
    } else {
      gm.outf[0] = gm.outf[1] = gm.outf[2] = nullptr;
      gm.outb[0] = xbf_g1; gm.outb[1] = xbf_d1; gm.outb[2] = xbf_c1;
      gm.out8[0] = x8_g1; gm.out8[1] = nullptr; gm.out8[2] = x8_c1;  // disease never gathered
    }
    gm.relu = (L == 0) ? 1 : 0;
    int gb = 0;
    for (int t = 0; t < 3; ++t) { gm.gbase[t] = gb; gb += (gm.M[t] + 127) / 128; }
    gm.gbase[3] = gb;
    k_gemm_all<<<gb, 256, 0, stream>>>(gm);
  }
}

// Round 24
// 310.243 us; speedup vs baseline: 2.2718x; 2.2718x over previous
//
#include <hip/hip_runtime.h>

// HeteroGNN: 2-layer hetero SAGE (gene/disease/compound), H=128.
// R24 = exact restore of R22/R20 (best known, ~311us). R23's (256,5) bound
// squeezed VGPR 64->48 and spilled the 64-reg accumulator to scratch
// (FETCH 208MB, WRITE 387MB, 254us/dispatch). (256,4) is the sweet spot:
// VGPR 64 no-spill, 4 blocks/CU; both neighbors (3 and 5 blocks) regress.
// Pipeline: memset, convert(NT loads), binA(EPB=1024), binB(512thr, PADRES),
// prepw, L0{agg,gemm}, L1{agg,gemm} = 9 launches.

constexpr int HD = 128;
constexpr int NBMAX = 512;      // max buckets (Ntot/1024 = 293 here)
constexpr int BSTRIDE = 32768;  // per-bucket record capacity
constexpr int EPB = 1024;       // edges per binA block (~8 blocks/CU)
constexpr int PADRES = 7176;    // per-bucket pad reserve (1024*7 + 8)

typedef __attribute__((ext_vector_type(8))) short bf16x8;
typedef __attribute__((ext_vector_type(16))) float f32x16;
typedef __attribute__((ext_vector_type(2))) float f32x2;
typedef __attribute__((ext_vector_type(4))) float f32x4;
typedef __attribute__((ext_vector_type(4))) unsigned int u32x4;

__device__ __forceinline__ unsigned short f2bf(float x) {
  unsigned u = __builtin_bit_cast(unsigned, x);
  u += 0x7FFF + ((u >> 16) & 1);  // RNE
  return (unsigned short)(u >> 16);
}
__device__ __forceinline__ float bf2f(unsigned short h) {
  return __builtin_bit_cast(float, (unsigned)h << 16);
}

// pack 8 f32 (x16 scale) -> 8 fp8 bytes (uint2)
__device__ __forceinline__ uint2 pack_fp8x8(const float* v) {
  uint2 o;
  unsigned t;
  t = (unsigned)__builtin_amdgcn_cvt_pk_fp8_f32(v[0] * 16.f, v[1] * 16.f, 0, false);
  t = (unsigned)__builtin_amdgcn_cvt_pk_fp8_f32(v[2] * 16.f, v[3] * 16.f, (int)t, true);
  o.x = t;
  t = (unsigned)__builtin_amdgcn_cvt_pk_fp8_f32(v[4] * 16.f, v[5] * 16.f, 0, false);
  t = (unsigned)__builtin_amdgcn_cvt_pk_fp8_f32(v[6] * 16.f, v[7] * 16.f, (int)t, true);
  o.y = t;
  return o;
}

// ---------------- f32 -> bf16 + fp8 table convert ----------------
__global__ __launch_bounds__(256) void k_convert(const float* __restrict__ s0,
                                                 const float* __restrict__ s1,
                                                 const float* __restrict__ s2,
                                                 unsigned short* __restrict__ d0,
                                                 unsigned short* __restrict__ d1,
                                                 unsigned short* __restrict__ d2,
                                                 unsigned char* __restrict__ e0,
                                                 unsigned char* __restrict__ e2,
                                                 long long n0, long long n1, long long n2) {
  long long i = ((long long)blockIdx.x * 256 + threadIdx.x) * 8;
  const float* s;
  unsigned short* d;
  unsigned char* e;
  if (i < n0) { s = s0 + i; d = d0 + i; e = e0 + i; }
  else if (i < n0 + n1) { s = s1 + (i - n0); d = d1 + (i - n0); e = nullptr; }  // disease: no fp8
  else if (i < n0 + n1 + n2) { s = s2 + (i - n0 - n1); d = d2 + (i - n0 - n1); e = e2 + (i - n0 - n1); }
  else return;
  f32x4 a = __builtin_nontemporal_load((const f32x4*)s);       // single-use stream
  f32x4 b = __builtin_nontemporal_load((const f32x4*)(s + 4));
  float v[8] = {a.x, a.y, a.z, a.w, b.x, b.y, b.z, b.w};
  uint4 o;
  o.x = (unsigned)f2bf(v[0]) | ((unsigned)f2bf(v[1]) << 16);
  o.y = (unsigned)f2bf(v[2]) | ((unsigned)f2bf(v[3]) << 16);
  o.z = (unsigned)f2bf(v[4]) | ((unsigned)f2bf(v[5]) << 16);
  o.w = (unsigned)f2bf(v[6]) | ((unsigned)f2bf(v[7]) << 16);
  *(uint4*)d = o;
  if (e) *(uint2*)e = pack_fp8x8(v);
}

// ---------------- CSR build ----------------
struct GArgs {
  const int* esrc[4];
  const int* edst[4];
  int ebase[5];  // edge prefix over concatenated edge space
  int nbase[4];  // dst-node prefix per relation (concat node space)
};

// Pass A: bin edges into 1024-node buckets; rec = (g&1023)<<20 | src.
__global__ __launch_bounds__(256) void k_binA(GArgs ga, int Etot, int NB,
                                              int* __restrict__ bucketCur,
                                              unsigned* __restrict__ binned) {
  __shared__ int hist[NBMAX];
  __shared__ int base[NBMAX];
  const int tid = threadIdx.x;
  for (int j = tid; j < NB; j += 256) hist[j] = 0;
  __syncthreads();
  const int e0 = blockIdx.x * EPB;
  for (int i = tid; i < EPB; i += 256) {
    int e = e0 + i;
    if (e < Etot) {
      int r = (e >= ga.ebase[1]) + (e >= ga.ebase[2]) + (e >= ga.ebase[3]);
      int g = ga.nbase[r] + ga.edst[r][e - ga.ebase[r]];
      atomicAdd(&hist[g >> 10], 1);
    }
  }
  __syncthreads();
  for (int j = tid; j < NB; j += 256) {
    int h = hist[j];
    base[j] = h ? atomicAdd(&bucketCur[j], h) : 0;
    hist[j] = 0;  // same thread owns j in both statements -> ordered
  }
  __syncthreads();
  for (int i = tid; i < EPB; i += 256) {
    int e = e0 + i;
    if (e < Etot) {
      int r = (e >= ga.ebase[1]) + (e >= ga.ebase[2]) + (e >= ga.ebase[3]);
      int el = e - ga.ebase[r];
      int g = ga.nbase[r] + ga.edst[r][el];
      int bk = g >> 10;
      int pos = base[bk] + atomicAdd(&hist[bk], 1);
      binned[(size_t)bk * BSTRIDE + pos] =
          ((unsigned)(g & 1023) << 20) | (unsigned)ga.esrc[r][el];
    }
  }
}

// Pass B: per-bucket CSR finalize, 512 threads; segments padded to 8 so the
// aggregate can load index quads via broadcast uint4.
__global__ __launch_bounds__(512) void k_binB(const int* __restrict__ bucketCur,
                                              const unsigned* __restrict__ binned,
                                              int* __restrict__ ptr, int* __restrict__ cnt,
                                              int* __restrict__ ss, int Ntot) {
  const int b = blockIdx.x;
  const int tid = threadIdx.x;
  __shared__ int ncnt[1024];
  __shared__ int noff[1024];
  __shared__ int red[512];
  __shared__ int sbase_s;
  __shared__ int wsum[8], wbase[8];

  int part = 0;
  for (int i = tid; i < b; i += 512) part += bucketCur[i];
  red[tid] = part;
  __syncthreads();
  for (int s = 256; s > 0; s >>= 1) {
    if (tid < s) red[tid] += red[tid + s];
    __syncthreads();
  }
  if (tid == 0) sbase_s = ((red[0] + 7) & ~7) + b * PADRES;  // 8-aligned base

  for (int j = tid; j < 1024; j += 512) ncnt[j] = 0;
  __syncthreads();

  const int ecount = bucketCur[b];
  const unsigned* bp = binned + (size_t)b * BSTRIDE;
  for (int i = tid; i < ecount; i += 512) atomicAdd(&ncnt[bp[i] >> 20], 1);
  __syncthreads();

  // exclusive scan over PADDED counts (2 nodes/thread, 8-wave scan)
  const int j0 = tid * 2;
  int c0 = ncnt[j0], c1 = ncnt[j0 + 1];
  int p0 = (c0 + 7) & ~7, p1 = (c1 + 7) & ~7;
  int s2 = p0 + p1;
  int lane = tid & 63, wid = tid >> 6;
  int incl = s2;
#pragma unroll
  for (int off = 1; off < 64; off <<= 1) {
    int t = __shfl_up(incl, off);
    if (lane >= off) incl += t;
  }
  if (lane == 63) wsum[wid] = incl;
  __syncthreads();
  if (tid == 0) {
    int acc = 0;
#pragma unroll
    for (int w2 = 0; w2 < 8; ++w2) { wbase[w2] = acc; acc += wsum[w2]; }
  }
  __syncthreads();
  int excl = wbase[wid] + incl - s2;
  const int sbase = sbase_s;
  int o0 = excl, o1 = o0 + p0;
  noff[j0] = o0; noff[j0 + 1] = o1;
  int g0 = b * 1024 + j0;
  if (g0 + 0 < Ntot) { ptr[g0 + 0] = sbase + o0; cnt[g0 + 0] = c0; }
  if (g0 + 1 < Ntot) { ptr[g0 + 1] = sbase + o1; cnt[g0 + 1] = c1; }
  __syncthreads();

  for (int i = tid; i < ecount; i += 512) {
    unsigned rec = bp[i];
    int j = rec >> 20;
    int p = sbase + atomicAdd(&noff[j], 1);
    ss[p] = (int)(rec & 0xFFFFF);
  }
}

// ---------------- W preprocessing ----------------
// W (or Wa+Wb) [k][n] f32 -> transposed [n][k] bf16, k swizzled:
// idx = n*128 + (k ^ ((n&15)<<3))  -> conflict-free ds_read_b128 in GEMM.
struct PrepArgs {
  const float* a[14];
  const float* b[14];
};

__global__ __launch_bounds__(256) void k_prepw(PrepArgs pa, unsigned short* __restrict__ out) {
  int s = blockIdx.x;
  const float* A = pa.a[s];
  const float* B = pa.b[s];
  unsigned short* oh = out + (size_t)s * 16384;
  int e0 = blockIdx.y * 1024 + threadIdx.x * 4;
#pragma unroll
  for (int j = 0; j < 4; ++j) {
    int e = e0 + j;
    int k = e >> 7, n = e & 127;
    float v = A[e] + (B ? B[e] : 0.f);
    oh[n * 128 + (k ^ ((n & 15) << 3))] = f2bf(v);
  }
}

// ---------------- fused neighbor mean (4 relations, fp8 gather) ----------------
struct AArgs {
  const unsigned char* xs[4];   // fp8 tables (x16 scale)
  unsigned short* mean[4];      // bf16 out
  int nbase[4];
  int bbase[5];  // block prefix
  int n[4];
};

__global__ __launch_bounds__(256) void k_aggregate_all(AArgs A, const int* __restrict__ ptr,
                                                       const int* __restrict__ cnt,
                                                       const int* __restrict__ ss) {
  int b = blockIdx.x;
  int r = (b >= A.bbase[1]) + (b >= A.bbase[2]) + (b >= A.bbase[3]);
  int d = (b - A.bbase[r]) * 32 + (threadIdx.x >> 3);
  if (d >= A.n[r]) return;
  const unsigned char* xs = A.xs[r];
  int l = threadIdx.x & 7;
  int g = A.nbase[r] + d;
  int p = ptr[g];   // multiple of 8 -> 16B-aligned index loads
  int deg = cnt[g];
  f32x2 b0 = {0.f, 0.f}, b1 = {0.f, 0.f}, b2 = {0.f, 0.f}, b3 = {0.f, 0.f};
  f32x2 b4 = {0.f, 0.f}, b5 = {0.f, 0.f}, b6 = {0.f, 0.f}, b7 = {0.f, 0.f};
  for (int j0 = 0; j0 < deg; j0 += 8) {
    int m = deg - j0;
    if (m > 8) m = 8;
    const uint4* ip = (const uint4*)(ss + p + j0);
    uint4 ia = ip[0];          // same addr across lanes -> broadcast
    uint4 ib = ip[1];          // pad slots may hold garbage; guarded below
    uint4 uu[8];
    if (m > 0) uu[0] = *(const uint4*)(xs + (size_t)ia.x * HD + l * 16);
    if (m > 1) uu[1] = *(const uint4*)(xs + (size_t)ia.y * HD + l * 16);
    if (m > 2) uu[2] = *(const uint4*)(xs + (size_t)ia.z * HD + l * 16);
    if (m > 3) uu[3] = *(const uint4*)(xs + (size_t)ia.w * HD + l * 16);
    if (m > 4) uu[4] = *(const uint4*)(xs + (size_t)ib.x * HD + l * 16);
    if (m > 5) uu[5] = *(const uint4*)(xs + (size_t)ib.y * HD + l * 16);
    if (m > 6) uu[6] = *(const uint4*)(xs + (size_t)ib.z * HD + l * 16);
    if (m > 7) uu[7] = *(const uint4*)(xs + (size_t)ib.w * HD + l * 16);
#pragma unroll
    for (int k = 0; k < 8; ++k) {
      if (k < m) {
        b0 += __builtin_amdgcn_cvt_pk_f32_fp8(uu[k].x, false);
        b1 += __builtin_amdgcn_cvt_pk_f32_fp8(uu[k].x, true);
        b2 += __builtin_amdgcn_cvt_pk_f32_fp8(uu[k].y, false);
        b3 += __builtin_amdgcn_cvt_pk_f32_fp8(uu[k].y, true);
        b4 += __builtin_amdgcn_cvt_pk_f32_fp8(uu[k].z, false);
        b5 += __builtin_amdgcn_cvt_pk_f32_fp8(uu[k].z, true);
        b6 += __builtin_amdgcn_cvt_pk_f32_fp8(uu[k].w, false);
        b7 += __builtin_amdgcn_cvt_pk_f32_fp8(uu[k].w, true);
      }
    }
  }
  float inv = 1.0f / (16.0f * (float)(deg > 0 ? deg : 1));  // fold out x16 scale
  u32x4 o;
  u32x4* mp = (u32x4*)(A.mean[r] + (size_t)d * HD + l * 16);
  o.x = (unsigned)f2bf(b0.x * inv) | ((unsigned)f2bf(b0.y * inv) << 16);
  o.y = (unsigned)f2bf(b1.x * inv) | ((unsigned)f2bf(b1.y * inv) << 16);
  o.z = (unsigned)f2bf(b2.x * inv) | ((unsigned)f2bf(b2.y * inv) << 16);
  o.w = (unsigned)f2bf(b3.x * inv) | ((unsigned)f2bf(b3.y * inv) << 16);
  mp[0] = o;  // plain (cached) store: means are the GEMM's A-operand
  o.x = (unsigned)f2bf(b4.x * inv) | ((unsigned)f2bf(b4.y * inv) << 16);
  o.y = (unsigned)f2bf(b5.x * inv) | ((unsigned)f2bf(b5.y * inv) << 16);
  o.z = (unsigned)f2bf(b6.x * inv) | ((unsigned)f2bf(b6.y * inv) << 16);
  o.w = (unsigned)f2bf(b7.x * inv) | ((unsigned)f2bf(b7.y * inv) << 16);
  mp[1] = o;  // +16B == +8 shorts
}

// ---------------- merged MFMA GEMM (3 node types, one dispatch) ----------------
// M-tile 128, 4 waves, wave owns 32 rows (acc[4]); R14-style A prefetch.
struct GemmArgs {
  const unsigned short* x[3][3];   // [type][slab]
  const unsigned short* wp[3][3];
  const float* b0[3];
  const float* b1[3];
  float* outf[3];                  // layer-1: d_out segment; layer-0: null
  unsigned short* outb[3];         // layer-0: bf16 hidden table
  unsigned char* out8[3];          // layer-0: fp8 hidden table (null = skip)
  int M[3];
  int nslab[3];
  int gbase[4];                    // block prefix per type
  int relu;
};

__global__ __launch_bounds__(256, 4) void k_gemm_all(GemmArgs ga) {
  __shared__ unsigned short ldsb[16384];  // 32KB
  const int t = (blockIdx.x >= ga.gbase[1]) + (blockIdx.x >= ga.gbase[2]);
  const int blk = blockIdx.x - ga.gbase[t];
  const int M = ga.M[t];
  const int nslab = ga.nslab[t];
  const int tid = threadIdx.x;
  const int wave = tid >> 6;
  const int lane = tid & 63;
  const int l31 = lane & 31;
  const int lhalf = lane >> 5;

  const int mbase = blk * 128 + wave * 32;
  int r0 = mbase + l31;
  if (r0 > M - 1) r0 = M - 1;

  f32x16 acc[4];
#pragma unroll
  for (int n = 0; n < 4; ++n)
#pragma unroll
    for (int q = 0; q < 16; ++q) acc[n][q] = 0.f;

#pragma unroll
  for (int s = 0; s < 3; ++s) {
    if (s < nslab) {
      const unsigned short* xp = ga.x[t][s] + (size_t)r0 * HD + lhalf * 8;
      // prefetch the wave's full A row for this slab: 8 independent 16B loads
      bf16x8 areg[8];
#pragma unroll
      for (int ks = 0; ks < 8; ++ks) areg[ks] = *(const bf16x8*)(xp + ks * 16);

      __syncthreads();  // protect LDS from previous slab's readers
      {
        const float4* src = (const float4*)ga.wp[t][s];
        float4* dst = (float4*)ldsb;
#pragma unroll
        for (int j = 0; j < 8; ++j) dst[tid + j * 256] = src[tid + j * 256];
      }
      __syncthreads();

#pragma unroll
      for (int ks = 0; ks < 8; ++ks) {
        const int k0 = ks * 16 + lhalf * 8;
#pragma unroll
        for (int nt = 0; nt < 4; ++nt) {
          const int rown = nt * 32 + l31;
          const int kidx = k0 ^ ((rown & 15) << 3);
          const bf16x8 bb = *(const bf16x8*)&ldsb[rown * HD + kidx];
          acc[nt] = __builtin_amdgcn_mfma_f32_32x32x16_bf16(areg[ks], bb, acc[nt], 0, 0, 0);
        }
      }
    }
  }

  const float* b0 = ga.b0[t];
  const float* b1 = ga.b1[t];
  float* outf = ga.outf[t];
  unsigned short* outb = ga.outb[t];
  unsigned char* out8 = ga.out8[t];
#pragma unroll
  for (int nt = 0; nt < 4; ++nt) {
    const int col = nt * 32 + l31;
    float bias = b0[col] + (b1 ? b1[col] : 0.f);
#pragma unroll
    for (int rg = 0; rg < 16; ++rg) {
      int row = mbase + (rg & 3) + 8 * (rg >> 2) + 4 * lhalf;
      float v = acc[nt][rg] + bias;
      if (ga.relu) v = fmaxf(v, 0.f);
      if (row < M) {
        if (outf) {
          outf[(size_t)row * HD + col] = v;
        } else {
          unsigned short h = f2bf(v);
          outb[(size_t)row * HD + col] = h;
          if (out8) {
            float vb = bf2f(h);  // bf16-rounded value (matches table semantics)
            unsigned pk = (unsigned)__builtin_amdgcn_cvt_pk_fp8_f32(vb * 16.f, vb * 16.f, 0, false);
            out8[(size_t)row * HD + col] = (unsigned char)(pk & 0xFF);
          }
        }
      }
    }
  }
}

extern "C" void kernel_launch(void* const* d_in, const int* in_sizes, int n_in,
                              void* d_out, int out_size, void* d_ws, size_t ws_size,
                              hipStream_t stream) {
  const float* emb_g = (const float*)d_in[0];
  const float* emb_d = (const float*)d_in[1];
  const float* emb_c = (const float*)d_in[2];
  const float* Wl = (const float*)d_in[3];   // [2,4,128,128]
  const float* bl = (const float*)d_in[4];   // [2,4,128]
  const float* Wr = (const float*)d_in[5];   // [2,4,128,128]

  const int NG = in_sizes[0] / HD;
  const int ND = in_sizes[1] / HD;
  const int NC = in_sizes[2] / HD;
  const int E0 = in_sizes[6];   // g->g
  const int E1 = in_sizes[8];   // c->d
  const int E2 = in_sizes[10];  // c->g
  const int E3 = in_sizes[12];  // g->c
  const int HH = HD * HD;
  const int Etot = E0 + E1 + E2 + E3;
  const int Ntot = NG + ND + NG + NC;
  const int NB = (Ntot + 1023) >> 10;  // 1024-node buckets

  // ---- workspace carve (all 16B-aligned by construction) ----
  char* w = (char*)d_ws;
  unsigned short* wprep = (unsigned short*)w; w += (size_t)14 * 32768;
  unsigned short* xbf_g0 = (unsigned short*)w; w += (size_t)NG * HD * 2;
  unsigned short* xbf_d0 = (unsigned short*)w; w += (size_t)ND * HD * 2;
  unsigned short* xbf_c0 = (unsigned short*)w; w += (size_t)NC * HD * 2;
  unsigned short* xbf_g1 = (unsigned short*)w; w += (size_t)NG * HD * 2;
  unsigned short* xbf_d1 = (unsigned short*)w; w += (size_t)ND * HD * 2;
  unsigned short* xbf_c1 = (unsigned short*)w; w += (size_t)NC * HD * 2;
  unsigned short* mean_gg = (unsigned short*)w; w += (size_t)NG * HD * 2;
  unsigned short* mean_cd = (unsigned short*)w; w += (size_t)ND * HD * 2;
  unsigned short* mean_cg = (unsigned short*)w; w += (size_t)NG * HD * 2;
  unsigned short* mean_gc = (unsigned short*)w; w += (size_t)NC * HD * 2;
  unsigned char* x8_g0 = (unsigned char*)w; w += (size_t)NG * HD;
  unsigned char* x8_c0 = (unsigned char*)w; w += (size_t)NC * HD;
  unsigned char* x8_g1 = (unsigned char*)w; w += (size_t)NG * HD;
  unsigned char* x8_c1 = (unsigned char*)w; w += (size_t)NC * HD;
  int* ss = (int*)w;        w += ((size_t)Etot + (size_t)NB * PADRES + 64) * 4;
  int* ptr = (int*)w;       w += (size_t)Ntot * 4;
  int* cnt = (int*)w;       w += (size_t)Ntot * 4;
  unsigned* binned = (unsigned*)w; w += (size_t)NB * BSTRIDE * 4;
  int* bucketCur = (int*)w; w += (size_t)NBMAX * 4;  // zeroed

  hipMemsetAsync(bucketCur, 0, (size_t)NBMAX * 4, stream);

  // bf16 (+fp8 for gene/compound) feature tables for layer 0
  {
    long long n0 = (long long)NG * HD, n1 = (long long)ND * HD, n2 = (long long)NC * HD;
    long long tot8 = (n0 + n1 + n2) / 8;
    k_convert<<<(int)((tot8 + 255) / 256), 256, 0, stream>>>(
        emb_g, emb_d, emb_c, xbf_g0, xbf_d0, xbf_c0, x8_g0, x8_c0, n0, n1, n2);
  }

  // CSR build over concatenated spaces (two-pass binned sort)
  GArgs ga;
  ga.esrc[0] = (const int*)d_in[6];  ga.edst[0] = (const int*)d_in[7];
  ga.esrc[1] = (const int*)d_in[8];  ga.edst[1] = (const int*)d_in[9];
  ga.esrc[2] = (const int*)d_in[10]; ga.edst[2] = (const int*)d_in[11];
  ga.esrc[3] = (const int*)d_in[12]; ga.edst[3] = (const int*)d_in[13];
  ga.ebase[0] = 0; ga.ebase[1] = E0; ga.ebase[2] = E0 + E1;
  ga.ebase[3] = E0 + E1 + E2; ga.ebase[4] = Etot;
  ga.nbase[0] = 0; ga.nbase[1] = NG; ga.nbase[2] = NG + ND; ga.nbase[3] = NG + ND + NG;

  k_binA<<<(Etot + EPB - 1) / EPB, 256, 0, stream>>>(ga, Etot, NB, bucketCur, binned);
  k_binB<<<NB, 512, 0, stream>>>(bucketCur, binned, ptr, cnt, ss, Ntot);

  // W preprocessing: 7 slabs/layer: 0:Wl0 1:Wl2 2:Wr0+Wr2 3:Wl1 4:Wr1 5:Wl3 6:Wr3
  PrepArgs pa;
  for (int L = 0; L < 2; ++L) {
    int b = L * 7;
    pa.a[b + 0] = Wl + (size_t)(L * 4 + 0) * HH; pa.b[b + 0] = nullptr;
    pa.a[b + 1] = Wl + (size_t)(L * 4 + 2) * HH; pa.b[b + 1] = nullptr;
    pa.a[b + 2] = Wr + (size_t)(L * 4 + 0) * HH; pa.b[b + 2] = Wr + (size_t)(L * 4 + 2) * HH;
    pa.a[b + 3] = Wl + (size_t)(L * 4 + 1) * HH; pa.b[b + 3] = nullptr;
    pa.a[b + 4] = Wr + (size_t)(L * 4 + 1) * HH; pa.b[b + 4] = nullptr;
    pa.a[b + 5] = Wl + (size_t)(L * 4 + 3) * HH; pa.b[b + 5] = nullptr;
    pa.a[b + 6] = Wr + (size_t)(L * 4 + 3) * HH; pa.b[b + 6] = nullptr;
  }
  k_prepw<<<dim3(14, 16), 256, 0, stream>>>(pa, wprep);

  float* out = (float*)d_out;
  float* xg_out = out;
  float* xd_out = out + (size_t)NG * HD;
  float* xc_out = out + (size_t)(NG + ND) * HD;

  for (int L = 0; L < 2; ++L) {
    const unsigned short* xg = L ? xbf_g1 : xbf_g0;
    const unsigned short* xd = L ? xbf_d1 : xbf_d0;
    const unsigned short* xc = L ? xbf_c1 : xbf_c0;
    const unsigned char* x8g = L ? x8_g1 : x8_g0;
    const unsigned char* x8c = L ? x8_c1 : x8_c0;

    // fused aggregates (reln order: gg(src xg), cd(src xc), cg(src xc), gc(src xg))
    AArgs aa;
    aa.xs[0] = x8g; aa.xs[1] = x8c; aa.xs[2] = x8c; aa.xs[3] = x8g;
    aa.mean[0] = mean_gg; aa.mean[1] = mean_cd; aa.mean[2] = mean_cg; aa.mean[3] = mean_gc;
    aa.nbase[0] = 0; aa.nbase[1] = NG; aa.nbase[2] = NG + ND; aa.nbase[3] = NG + ND + NG;
    aa.n[0] = NG; aa.n[1] = ND; aa.n[2] = NG; aa.n[3] = NC;
    int bb = 0;
    for (int r = 0; r < 4; ++r) { aa.bbase[r] = bb; bb += (aa.n[r] + 31) / 32; }
    aa.bbase[4] = bb;
    k_aggregate_all<<<bb, 256, 0, stream>>>(aa, ptr, cnt, ss);

    const float* bl_L = bl + (size_t)L * 4 * HD;
    const unsigned short* wp = wprep + (size_t)L * 7 * 16384;

    GemmArgs gm;
    // genes: mean_gg@Wl0 + mean_cg@Wl2 + xg@(Wr0+Wr2) + bl0 + bl2
    gm.x[0][0] = mean_gg; gm.x[0][1] = mean_cg; gm.x[0][2] = xg;
    gm.wp[0][0] = wp + 0 * 16384; gm.wp[0][1] = wp + 1 * 16384; gm.wp[0][2] = wp + 2 * 16384;
    gm.b0[0] = bl_L + 0 * HD; gm.b1[0] = bl_L + 2 * HD;
    gm.M[0] = NG; gm.nslab[0] = 3;
    // disease: mean_cd@Wl1 + xd@Wr1 + bl1
    gm.x[1][0] = mean_cd; gm.x[1][1] = xd; gm.x[1][2] = nullptr;
    gm.wp[1][0] = wp + 3 * 16384; gm.wp[1][1] = wp + 4 * 16384; gm.wp[1][2] = nullptr;
    gm.b0[1] = bl_L + 1 * HD; gm.b1[1] = nullptr;
    gm.M[1] = ND; gm.nslab[1] = 2;
    // compound: mean_gc@Wl3 + xc@Wr3 + bl3
    gm.x[2][0] = mean_gc; gm.x[2][1] = xc; gm.x[2][2] = nullptr;
    gm.wp[2][0] = wp + 5 * 16384; gm.wp[2][1] = wp + 6 * 16384; gm.wp[2][2] = nullptr;
    gm.b0[2] = bl_L + 3 * HD; gm.b1[2] = nullptr;
    gm.M[2] = NC; gm.nslab[2] = 2;
    if (L) {
      gm.outf[0] = xg_out; gm.outf[1] = xd_out; gm.outf[2] = xc_out;
      gm.outb[0] = gm.outb[1] = gm.outb[2] = nullptr;
      gm.out8[0] = gm.out8[1] = gm.out8[2] = nullptr;
    } else {
      gm.outf[0] = gm.outf[1] = gm.outf[2] = nullptr;
      gm.outb[0] = xbf_g1; gm.outb[1] = xbf_d1; gm.outb[2] = xbf_c1;
      gm.out8[0] = x8_g1; gm.out8[1] = nullptr; gm.out8[2] = x8_c1;  // disease never gathered
    }
    gm.relu = (L == 0) ? 1 : 0;
    int gb = 0;
    for (int t = 0; t < 3; ++t) { gm.gbase[t] = gb; gb += (gm.M[t] + 127) / 128; }
    gm.gbase[3] = gb;
    k_gemm_all<<<gb, 256, 0, stream>>>(gm);
  }
}